// Round 1
// baseline (460.866 us; speedup 1.0000x reference)
//
#include <hip/hip_runtime.h>
#include <hip/hip_bf16.h>
#include <stdint.h>

#define B_   16
#define CIN  512
#define HW   1600
#define E_   256
#define NTOK 80
#define CG   512
#define COUT 512
#define NHEAD 8
#define HCH  32
#define SP   (42*42)   /* padded spatial 42x42 = 1764 */

typedef __attribute__((ext_vector_type(8))) short bf16x8;
typedef __attribute__((ext_vector_type(4))) float f32x4;

__device__ __forceinline__ float bf2f(unsigned short u) {
  union { unsigned int i; float f; } v; v.i = ((unsigned int)u) << 16; return v.f;
}
__device__ __forceinline__ unsigned short f2bf(float f) {
  union { float f; unsigned int i; } v; v.f = f;
  unsigned int x = v.i;
  return (unsigned short)((x + 0x7FFFu + ((x >> 16) & 1u)) >> 16);
}

// ---- prep: x [B][CIN][HW] f32 -> xt [B][SP][CIN] bf16 (zero border pad=1) ----
__global__ void k_prep_x(const float* __restrict__ x, unsigned short* __restrict__ xt) {
  __shared__ float tile[32][33];
  int hw0 = blockIdx.x * 32, ci0 = blockIdx.y * 32, b = blockIdx.z;
  int tx = threadIdx.x, ty = threadIdx.y;
  const float* xp = x + ((size_t)b * CIN + ci0) * HW + hw0;
#pragma unroll
  for (int j = 0; j < 4; j++) tile[ty + 8 * j][tx] = xp[(size_t)(ty + 8 * j) * HW + tx];
  __syncthreads();
  int ci = ci0 + tx;
#pragma unroll
  for (int j = 0; j < 4; j++) {
    int hw = hw0 + ty + 8 * j;
    int h = hw / 40, w = hw - h * 40;
    xt[((size_t)b * SP + (size_t)(h + 1) * 42 + (w + 1)) * CIN + ci] = f2bf(tile[tx][ty + 8 * j]);
  }
}

// ---- prep: Wp [COUT][CIN][3][3] f32 -> wpb [9][COUT][CIN] bf16 ----
__global__ void k_prep_wp(const float* __restrict__ Wp, unsigned short* __restrict__ wpb) {
  int idx = blockIdx.x * 256 + threadIdx.x;   // 0..262143 = co*512+ci
  int co = idx >> 9, ci = idx & 511;
  const float* s = Wp + (size_t)idx * 9;
#pragma unroll
  for (int t = 0; t < 9; t++) wpb[((size_t)t * COUT + co) * CIN + ci] = f2bf(s[t]);
}

// ---- prep: We [E][CIN] f32 -> web bf16 ----
__global__ void k_prep_we(const float* __restrict__ We, unsigned short* __restrict__ web) {
  int idx = blockIdx.x * 256 + threadIdx.x;
  if (idx < E_ * CIN) web[idx] = f2bf(We[idx]);
}

// ---- guide_fc: g[b][n][e] = guide[b][n][:] . Wg[e][:] + bg[e] ----
__global__ void k_guide(const float* __restrict__ guide, const float* __restrict__ Wg,
                        const float* __restrict__ bg, float* __restrict__ g) {
  __shared__ float gr[512];
  int bn = blockIdx.x; int tid = threadIdx.x;
  const float* gp = guide + (size_t)bn * CG;
  gr[tid] = gp[tid]; gr[tid + 256] = gp[tid + 256];
  __syncthreads();
  const float4* wr4 = (const float4*)(Wg + (size_t)tid * CG);
  float acc = bg[tid];
#pragma unroll 8
  for (int c4 = 0; c4 < 128; c4++) {
    float4 wv = wr4[c4];
    const float* gg = &gr[c4 * 4];
    acc += wv.x * gg[0] + wv.y * gg[1] + wv.z * gg[2] + wv.w * gg[3];
  }
  g[(size_t)bn * E_ + tid] = acc;
}

// ---- implicit-GEMM conv (bf16 MFMA, 128x128 tile, BK=32, m97 structure) ----
// EPI==0: conv1x1 path -> et[b][hw][E] bf16 with BN
// EPI==1: conv3x3 path -> out[b][co][hw] f32 with BN * attn gate
template<int NTAPS, int EPI>
__launch_bounds__(256)
__global__ void k_conv(const unsigned short* __restrict__ Aw, // [NTAPS][Mtot][CIN]
                       const unsigned short* __restrict__ xt, // [B][SP][CIN]
                       const float* __restrict__ gamma, const float* __restrict__ beta,
                       const float* __restrict__ attn, float* __restrict__ outp,
                       unsigned short* __restrict__ et, int Mtot) {
  __shared__ unsigned short Al[128 * 32];
  __shared__ unsigned short Bl[128 * 32];
  int tid = threadIdx.x;
  int b = blockIdx.z;
  int m0 = blockIdx.x * 128, n0 = blockIdx.y * 128;
  int lane = tid & 63, wid = tid >> 6;
  int wr = wid >> 1, wc = wid & 1;

  // staging geometry: 512 chunks of 16B per tile; thread stages chunk tid and tid+256
  int mA = tid >> 2;               // row (A) / n (B) for chunk0; chunk1 = +64
  int kg = (tid & 3) * 8;          // element offset within BK
  int hw_a = n0 + mA;     if (hw_a > HW - 1) hw_a = HW - 1;
  int hw_b = n0 + mA + 64; if (hw_b > HW - 1) hw_b = HW - 1;
  int ha = hw_a / 40, wa = hw_a - ha * 40;
  int hb = hw_b / 40, wb = hw_b - hb * 40;
  int sp_a = ha * 42 + wa, sp_b = hb * 42 + wb;
  const unsigned short* xtb = xt + (size_t)b * SP * CIN;

  char* AlB = (char*)Al; char* BlB = (char*)Bl;
  unsigned int lds0 = (unsigned int)tid * 16u, lds1 = (unsigned int)tid * 16u + 4096u;

  int frow = lane & 15;
  int fkb = (lane >> 4) * 16;       // byte offset of this lane's k-granule
  int aoffs[4], boffs[4];
#pragma unroll
  for (int i = 0; i < 4; i++) {
    aoffs[i] = (wr * 64 + i * 16 + frow) * 64 + fkb;
    boffs[i] = (wc * 64 + i * 16 + frow) * 64 + fkb;
  }

  f32x4 acc[4][4] = {};

  for (int t = 0; t < NTAPS; ++t) {
    int th = (NTAPS == 1) ? 1 : (t / 3);
    int tw = (NTAPS == 1) ? 1 : (t - (t / 3) * 3);
    const unsigned short* Ab = Aw + ((size_t)t * Mtot + m0) * CIN + (size_t)mA * CIN + kg;
    const unsigned short* Bb0 = xtb + (size_t)(sp_a + th * 42 + tw) * CIN + kg;
    const unsigned short* Bb1 = xtb + (size_t)(sp_b + th * 42 + tw) * CIN + kg;
    for (int kk = 0; kk < CIN; kk += 32) {
      const unsigned short* s0 = Ab + kk;
      const unsigned short* s1 = s0 + 64 * CIN;
      __builtin_amdgcn_global_load_lds((const __attribute__((address_space(1))) unsigned int*)s0,
          (__attribute__((address_space(3))) unsigned int*)(AlB + lds0), 16, 0, 0);
      __builtin_amdgcn_global_load_lds((const __attribute__((address_space(1))) unsigned int*)s1,
          (__attribute__((address_space(3))) unsigned int*)(AlB + lds1), 16, 0, 0);
      __builtin_amdgcn_global_load_lds((const __attribute__((address_space(1))) unsigned int*)(Bb0 + kk),
          (__attribute__((address_space(3))) unsigned int*)(BlB + lds0), 16, 0, 0);
      __builtin_amdgcn_global_load_lds((const __attribute__((address_space(1))) unsigned int*)(Bb1 + kk),
          (__attribute__((address_space(3))) unsigned int*)(BlB + lds1), 16, 0, 0);
      __syncthreads();
      bf16x8 af[4], bf[4];
#pragma unroll
      for (int i = 0; i < 4; i++) af[i] = *(const bf16x8*)(AlB + aoffs[i]);
#pragma unroll
      for (int i = 0; i < 4; i++) bf[i] = *(const bf16x8*)(BlB + boffs[i]);
#pragma unroll
      for (int mi = 0; mi < 4; mi++)
#pragma unroll
        for (int ni = 0; ni < 4; ni++)
          acc[mi][ni] = __builtin_amdgcn_mfma_f32_16x16x32_bf16(af[mi], bf[ni], acc[mi][ni], 0, 0, 0);
      __syncthreads();
    }
  }

  const float BN_RSQ = 0.9995003746877732f;  // 1/sqrt(1+1e-3)
  int colb = n0 + wc * 64 + frow;
  int rowb = m0 + wr * 64 + (lane >> 4) * 4;
  if (EPI == 1) {
    int head = (m0 + wr * 64) >> 6;           // 64 channels per head, uniform per wave
    const float* attn_b = attn + ((size_t)b * NHEAD + head) * HW;
    float* ob = outp + (size_t)b * COUT * HW;
#pragma unroll
    for (int mi = 0; mi < 4; mi++) {
      float sc[4], bt[4];
#pragma unroll
      for (int j = 0; j < 4; j++) {
        int co = rowb + mi * 16 + j;
        sc[j] = gamma[co] * BN_RSQ; bt[j] = beta[co];
      }
#pragma unroll
      for (int ni = 0; ni < 4; ni++) {
        int hw = colb + ni * 16;
        if (hw < HW) {
          float gate = attn_b[hw];
#pragma unroll
          for (int j = 0; j < 4; j++) {
            int co = rowb + mi * 16 + j;
            ob[(size_t)co * HW + hw] = (acc[mi][ni][j] * sc[j] + bt[j]) * gate;
          }
        }
      }
    }
  } else {
#pragma unroll
    for (int mi = 0; mi < 4; mi++) {
      float sc[4], bt[4];
#pragma unroll
      for (int j = 0; j < 4; j++) {
        int ech = rowb + mi * 16 + j;
        sc[j] = gamma[ech] * BN_RSQ; bt[j] = beta[ech];
      }
#pragma unroll
      for (int ni = 0; ni < 4; ni++) {
        int hw = colb + ni * 16;
        if (hw < HW) {
          ushort4 pk;
          pk.x = f2bf(acc[mi][ni][0] * sc[0] + bt[0]);
          pk.y = f2bf(acc[mi][ni][1] * sc[1] + bt[1]);
          pk.z = f2bf(acc[mi][ni][2] * sc[2] + bt[2]);
          pk.w = f2bf(acc[mi][ni][3] * sc[3] + bt[3]);
          *(ushort4*)(et + ((size_t)b * HW + hw) * E_ + (rowb + mi * 16)) = pk;
        }
      }
    }
  }
}

// ---- attn: max_n( e[b,m,:,hw] . g[b,n,m,:] ) / sqrt(32) + bias -> sigmoid ----
__global__ void k_attn(const unsigned short* __restrict__ et, const float* __restrict__ g,
                       const float* __restrict__ head_bias, float* __restrict__ attn) {
  __shared__ float gs[NTOK * HCH];
  int b = blockIdx.z, m = blockIdx.y;
  int tid = threadIdx.x;
  const float* gb = g + (size_t)b * NTOK * E_ + m * HCH;
  for (int i = tid; i < NTOK * HCH; i += 256) {
    int n = i >> 5, c = i & 31;
    gs[i] = gb[(size_t)n * E_ + c];
  }
  __syncthreads();
  int hw = blockIdx.x * 256 + tid;
  if (hw >= HW) return;
  const uint4* ep4 = (const uint4*)(et + ((size_t)b * HW + hw) * E_ + m * HCH);
  float ev[32];
#pragma unroll
  for (int q = 0; q < 4; q++) {
    uint4 r = ep4[q];
    unsigned int uu[4] = {r.x, r.y, r.z, r.w};
#pragma unroll
    for (int k = 0; k < 4; k++) {
      union { unsigned int i; float f; } lo, hi;
      lo.i = uu[k] << 16; hi.i = uu[k] & 0xffff0000u;
      ev[q * 8 + k * 2] = lo.f; ev[q * 8 + k * 2 + 1] = hi.f;
    }
  }
  float best = -1e30f;
  for (int n = 0; n < NTOK; n++) {
    const float* gn = &gs[n * 32];
    float d = 0.f;
#pragma unroll
    for (int c = 0; c < 32; c++) d += ev[c] * gn[c];
    best = fmaxf(best, d);
  }
  best = best * 0.17677669529663687f + head_bias[m];   // 1/sqrt(32)
  float sig = 1.0f / (1.0f + __expf(-best));
  attn[((size_t)b * NHEAD + m) * HW + hw] = sig;
}

extern "C" void kernel_launch(void* const* d_in, const int* in_sizes, int n_in,
                              void* d_out, int out_size, void* d_ws, size_t ws_size,
                              hipStream_t stream) {
  const float* x         = (const float*)d_in[0];
  const float* guide     = (const float*)d_in[1];
  const float* We        = (const float*)d_in[2];
  const float* gamma_e   = (const float*)d_in[3];
  const float* beta_e    = (const float*)d_in[4];
  const float* Wg        = (const float*)d_in[5];
  const float* bg        = (const float*)d_in[6];
  const float* head_bias = (const float*)d_in[7];
  const float* Wp        = (const float*)d_in[8];
  const float* gamma_p   = (const float*)d_in[9];
  const float* beta_p    = (const float*)d_in[10];
  float* out = (float*)d_out;

  char* ws = (char*)d_ws;
  size_t off = 0;
  auto alloc = [&](size_t bytes) { char* p = ws + off; off += (bytes + 255) & ~(size_t)255; return p; };
  unsigned short* xt  = (unsigned short*)alloc((size_t)B_ * SP * CIN * 2);
  unsigned short* wpb = (unsigned short*)alloc((size_t)9 * COUT * CIN * 2);
  unsigned short* web = (unsigned short*)alloc((size_t)E_ * CIN * 2);
  float* g            = (float*)alloc((size_t)B_ * NTOK * E_ * 4);
  unsigned short* et  = (unsigned short*)alloc((size_t)B_ * HW * E_ * 2);
  float* attn         = (float*)alloc((size_t)B_ * NHEAD * HW * 4);

  hipMemsetAsync(xt, 0, (size_t)B_ * SP * CIN * 2, stream);
  k_prep_x<<<dim3(50, 16, B_), dim3(32, 8), 0, stream>>>(x, xt);
  k_prep_wp<<<dim3(1024), dim3(256), 0, stream>>>(Wp, wpb);
  k_prep_we<<<dim3(512), dim3(256), 0, stream>>>(We, web);
  k_guide<<<dim3(B_ * NTOK), dim3(256), 0, stream>>>(guide, Wg, bg, g);
  k_conv<1, 0><<<dim3(2, 13, B_), dim3(256), 0, stream>>>(web, xt, gamma_e, beta_e, nullptr, nullptr, et, E_);
  k_attn<<<dim3(7, NHEAD, B_), dim3(256), 0, stream>>>(et, g, head_bias, attn);
  k_conv<9, 1><<<dim3(4, 13, B_), dim3(256), 0, stream>>>(wpb, xt, gamma_p, beta_p, attn, out, nullptr, COUT);
}